// Round 1
// baseline (188.435 us; speedup 1.0000x reference)
//
#include <hip/hip_runtime.h>
#include <math.h>

#define GS 8
#define HC 60
#define WC 80
#define NN 4800      // HC*WC
#define CC 64
#define BB 2
#define HIMG 480
#define WIMG 640
#define EPSF 1e-8f
#define CSPLIT 4
#define COLS_PER_SPLIT 1200   // NN / CSPLIT
#define TILE 256
#define RPB 32                // rows per block (4 waves x 8 rows)

// ---------------- per-cell prep: warp, pos_sim, match, top-4 neighbors ----------------
__global__ void k_prep(const float* __restrict__ desc1,
                       const float* __restrict__ desc2,
                       const float* __restrict__ homo12,
                       float* __restrict__ posim,
                       float* __restrict__ matchm,
                       int*   __restrict__ neigh)
{
    int idx = blockIdx.x * 256 + threadIdx.x;
    if (idx >= BB * NN) return;
    int b = idx / NN, r = idx - b * NN;
    int ci = r / WC, cj = r - ci * WC;
    float x = cj * 8.0f + 3.5f;   // grid-cell center (exact small floats)
    float y = ci * 8.0f + 3.5f;
    const float* h = homo12 + b * 9;
    float qx = h[0]*x + h[1]*y + h[2];
    float qy = h[3]*x + h[4]*y + h[5];
    float qw = h[6]*x + h[7]*y + h[8];
    float wx = qx / (qw + EPSF);
    float wy = qy / (qw + EPSF);

    matchm[idx] = (wy >= 0.0f && wy <= (float)(HIMG-1) &&
                   wx >= 0.0f && wx <= (float)(WIMG-1)) ? 1.0f : 0.0f;

    // d_yx = (w_yx - gs/2 + 0.5) / gs  -- replicate op order
    float dy = (wy - 4.0f + 0.5f) / 8.0f;
    float dx = (wx - 4.0f + 0.5f) / 8.0f;

    // ---- bilinear sample of desc2 at (dy, dx) ----
    float y0f = floorf(dy), x0f = floorf(dx);
    float fy = dy - y0f, fx = dx - x0f;
    float y1f = y0f + 1.0f, x1f = x0f + 1.0f;
    bool v0y = (y0f >= 0.0f && y0f <= (float)(HC-1));
    bool v1y = (y1f >= 0.0f && y1f <= (float)(HC-1));
    bool v0x = (x0f >= 0.0f && x0f <= (float)(WC-1));
    bool v1x = (x1f >= 0.0f && x1f <= (float)(WC-1));
    float w00 = (1.0f-fy)*(1.0f-fx); if (!(v0y && v0x)) w00 = 0.0f;
    float w01 = (1.0f-fy)*fx;        if (!(v0y && v1x)) w01 = 0.0f;
    float w10 = fy*(1.0f-fx);        if (!(v1y && v0x)) w10 = 0.0f;
    float w11 = fy*fx;               if (!(v1y && v1x)) w11 = 0.0f;
    int yc0 = (int)fminf(fmaxf(y0f, 0.0f), (float)(HC-1));
    int yc1 = (int)fminf(fmaxf(y1f, 0.0f), (float)(HC-1));
    int xc0 = (int)fminf(fmaxf(x0f, 0.0f), (float)(WC-1));
    int xc1 = (int)fminf(fmaxf(x1f, 0.0f), (float)(WC-1));
    int o00 = yc0*WC + xc0, o01 = yc0*WC + xc1;
    int o10 = yc1*WC + xc0, o11 = yc1*WC + xc1;

    const float* d2b = desc2 + (size_t)b * CC * NN;
    const float* d1b = desc1 + (size_t)b * CC * NN;
    float s2 = 0.0f, sd = 0.0f;
    for (int ch = 0; ch < CC; ch++) {
        const float* p = d2b + ch * NN;
        float wv = w00*p[o00] + w01*p[o01] + w10*p[o10] + w11*p[o11];
        s2 += wv * wv;
        sd += d1b[ch*NN + r] * wv;
    }
    float dot = sd / (sqrtf(s2) + EPSF);
    posim[idx] = sqrtf(fmaxf(2.0f - 2.0f*dot, EPSF));

    // ---- top-4 nearest grid centers to (wy, wx) ----
    int i0 = (int)floorf(dy);
    int j0 = (int)floorf(dx);
    int ilo = i0 - 1; if (ilo < 0) ilo = 0; if (ilo > HC-4) ilo = HC-4;
    int jlo = j0 - 1; if (jlo < 0) jlo = 0; if (jlo > WC-4) jlo = WC-4;
    float bd0=3e38f, bd1=3e38f, bd2=3e38f, bd3=3e38f;
    int   id0=0,     id1=0,     id2=0,     id3=0;
    #pragma unroll
    for (int a = 0; a < 4; a++) {
        float cy = (float)(ilo + a) * 8.0f + 3.5f;
        float ddy = wy - cy;
        float ddy2 = ddy * ddy;
        #pragma unroll
        for (int q = 0; q < 4; q++) {
            float cx = (float)(jlo + q) * 8.0f + 3.5f;
            float ddx = wx - cx;
            float dv = ddy2 + ddx * ddx;
            int id = (ilo + a) * WC + (jlo + q);
            if (dv < bd3) {             // strict: lower index wins ties
                bd3 = dv; id3 = id;
                if (bd3 < bd2) { float tf=bd2; bd2=bd3; bd3=tf; int ti=id2; id2=id3; id3=ti; }
                if (bd2 < bd1) { float tf=bd1; bd1=bd2; bd2=tf; int ti=id1; id1=id2; id2=ti; }
                if (bd1 < bd0) { float tf=bd0; bd0=bd1; bd1=tf; int ti=id0; id0=id1; id1=ti; }
            }
        }
    }
    neigh[idx*4+0] = id0; neigh[idx*4+1] = id1;
    neigh[idx*4+2] = id2; neigh[idx*4+3] = id3;
}

// ---------------- visibility mask per cell (all 64 pixels visible under homo21) ----------------
__global__ void k_vis(const float* __restrict__ homo21, float* __restrict__ vism)
{
    int idx = blockIdx.x * 256 + threadIdx.x;
    if (idx >= BB * NN) return;
    int b = idx / NN, r = idx - b * NN;
    int ci = r / WC, cj = r - ci * WC;
    const float* h = homo21 + b * 9;
    bool all = true;
    for (int di = 0; di < GS && all; di++) {
        float y = (float)(ci * 8 + di);
        for (int dj = 0; dj < GS; dj++) {
            float x = (float)(cj * 8 + dj);
            float qx = h[0]*x + h[1]*y + h[2];
            float qy = h[3]*x + h[4]*y + h[5];
            float qw = h[6]*x + h[7]*y + h[8];
            float px = qx / (qw + EPSF);
            float py = qy / (qw + EPSF);
            float y0 = floorf(py), x0 = floorf(px);
            float ty = py - y0,   tx = px - x0;
            float fyv = ((y0 >= 0.0f && y0 <= (float)(HIMG-1)) ? (1.0f-ty) : 0.0f)
                      + ((y0+1.0f >= 0.0f && y0+1.0f <= (float)(HIMG-1)) ? ty : 0.0f);
            float fxv = ((x0 >= 0.0f && x0 <= (float)(WIMG-1)) ? (1.0f-tx) : 0.0f)
                      + ((x0+1.0f >= 0.0f && x0+1.0f <= (float)(WIMG-1)) ? tx : 0.0f);
            if (!(fyv > 0.0f && fxv > 0.0f)) { all = false; break; }
        }
    }
    vism[idx] = all ? 1.0f : 0.0f;
}

// ---------------- fused GEMM + masked min:  neg partials over a 1/4 column split ----------------
__global__ __launch_bounds__(256) void k_negmin(
    const float* __restrict__ desc1, const float* __restrict__ desc2,
    const float* __restrict__ vism, const int* __restrict__ neigh,
    float* __restrict__ negpart)
{
    __shared__ float d2t[CC * TILE];    // [ch][col] 64x256 = 64 KB
    __shared__ float d1t[RPB * CC];     // [row][ch] 32x64 = 8 KB
    __shared__ int   idsh[RPB * 4];

    int bid = blockIdx.x;
    int cs = bid & (CSPLIT - 1);
    int tmp = bid >> 2;
    int rblk = tmp % (NN / RPB);
    int b = tmp / (NN / RPB);
    int r0 = rblk * RPB;
    int tid = threadIdx.x;

    #pragma unroll
    for (int k = 0; k < 8; k++) {
        int rl = tid & 31;
        int ch = (tid >> 5) + k * 8;
        d1t[rl * CC + ch] = desc1[(b * CC + ch) * NN + r0 + rl];
    }
    if (tid < RPB * 4) idsh[tid] = neigh[(b * NN + r0) * 4 + tid];
    __syncthreads();

    int w = tid >> 6;
    int L = tid & 63;
    int wr = w * 8;

    int nid[8][4];
    #pragma unroll
    for (int rr = 0; rr < 8; rr++)
        #pragma unroll
        for (int q = 0; q < 4; q++)
            nid[rr][q] = idsh[(wr + rr) * 4 + q];

    float negmin[8];
    #pragma unroll
    for (int rr = 0; rr < 8; rr++) negmin[rr] = 3.0e38f;

    int colbase = cs * COLS_PER_SPLIT;
    int collim  = colbase + COLS_PER_SPLIT;

    for (int t = 0; t < 5; t++) {
        int col0 = colbase + t * TILE;
        __syncthreads();
        #pragma unroll
        for (int k = 0; k < 16; k++) {
            int f4 = k * 256 + tid;
            int ch = f4 >> 6;
            int cg = f4 & 63;
            int col = col0 + cg * 4;
            float4 v;
            if (col < collim)   // collim % 4 == 0 -> whole float4 in/out
                v = *reinterpret_cast<const float4*>(&desc2[(b * CC + ch) * NN + col]);
            else
                v = make_float4(0.f, 0.f, 0.f, 0.f);
            *reinterpret_cast<float4*>(&d2t[ch * TILE + cg * 4]) = v;
        }
        __syncthreads();

        float acc[8][4];
        #pragma unroll
        for (int rr = 0; rr < 8; rr++) { acc[rr][0]=0.f; acc[rr][1]=0.f; acc[rr][2]=0.f; acc[rr][3]=0.f; }

        for (int chg = 0; chg < 16; chg++) {
            float4 a[8];
            #pragma unroll
            for (int rr = 0; rr < 8; rr++)
                a[rr] = *reinterpret_cast<const float4*>(&d1t[(wr + rr) * CC + chg * 4]);
            #pragma unroll
            for (int cc = 0; cc < 4; cc++) {
                float4 v = *reinterpret_cast<const float4*>(&d2t[(chg * 4 + cc) * TILE + L * 4]);
                #pragma unroll
                for (int rr = 0; rr < 8; rr++) {
                    float av = (cc == 0) ? a[rr].x : (cc == 1) ? a[rr].y : (cc == 2) ? a[rr].z : a[rr].w;
                    acc[rr][0] += av * v.x;
                    acc[rr][1] += av * v.y;
                    acc[rr][2] += av * v.z;
                    acc[rr][3] += av * v.w;
                }
            }
        }

        int vcol = col0 + L * 4;
        if (vcol < collim) {
            float4 vv = *reinterpret_cast<const float4*>(&vism[b * NN + vcol]);
            float vpen[4] = { 5.0f*(1.0f-vv.x), 5.0f*(1.0f-vv.y), 5.0f*(1.0f-vv.z), 5.0f*(1.0f-vv.w) };
            #pragma unroll
            for (int rr = 0; rr < 8; rr++) {
                #pragma unroll
                for (int q = 0; q < 4; q++) {
                    int col = vcol + q;
                    float s = acc[rr][q];
                    float val = sqrtf(fmaxf(2.0f - 2.0f*s, EPSF)) + vpen[q];
                    if (col == nid[rr][0] || col == nid[rr][1] ||
                        col == nid[rr][2] || col == nid[rr][3]) val += 5.0f;
                    negmin[rr] = fminf(negmin[rr], val);
                }
            }
        }
    }

    #pragma unroll
    for (int rr = 0; rr < 8; rr++) {
        float m = negmin[rr];
        #pragma unroll
        for (int off = 32; off >= 1; off >>= 1)
            m = fminf(m, __shfl_xor(m, off));
        if (L == 0)
            negpart[(b * NN + r0 + wr + rr) * CSPLIT + cs] = m;
    }
}

// ---------------- final loss reduction ----------------
__global__ void k_final(const float* __restrict__ posim, const float* __restrict__ matchm,
                        const float* __restrict__ negpart, float* __restrict__ out)
{
    __shared__ float sn[256], sdn[256];
    int tid = threadIdx.x;
    float num = 0.0f, den = 0.0f;
    for (int i = tid; i < BB * NN; i += 256) {
        float a = negpart[i*4+0], b = negpart[i*4+1];
        float c = negpart[i*4+2], d = negpart[i*4+3];
        float neg = fminf(fminf(a, b), fminf(c, d));
        float l = fmaxf(posim[i] - neg + 1.0f, 0.0f);
        float mm = matchm[i];
        num += l * l * mm;
        den += mm;
    }
    sn[tid] = num; sdn[tid] = den;
    __syncthreads();
    for (int s = 128; s > 0; s >>= 1) {
        if (tid < s) { sn[tid] += sn[tid + s]; sdn[tid] += sdn[tid + s]; }
        __syncthreads();
    }
    if (tid == 0) out[0] = sn[0] / sdn[0];
}

extern "C" void kernel_launch(void* const* d_in, const int* in_sizes, int n_in,
                              void* d_out, int out_size, void* d_ws, size_t ws_size,
                              hipStream_t stream)
{
    const float* desc1  = (const float*)d_in[2];
    const float* desc2  = (const float*)d_in[3];
    const float* homo12 = (const float*)d_in[4];
    const float* homo21 = (const float*)d_in[5];
    float* out = (float*)d_out;

    float* vis     = (float*)d_ws;            // B*N
    float* posim   = vis + BB * NN;           // B*N
    float* matchm  = posim + BB * NN;         // B*N
    float* negpart = matchm + BB * NN;        // B*N*4
    int*   neigh   = (int*)(negpart + BB * NN * CSPLIT);  // B*N*4

    int nitems = BB * NN;
    k_vis<<<(nitems + 255) / 256, 256, 0, stream>>>(homo21, vis);
    k_prep<<<(nitems + 255) / 256, 256, 0, stream>>>(desc1, desc2, homo12, posim, matchm, neigh);
    int nblocks = BB * (NN / RPB) * CSPLIT;   // 1200
    k_negmin<<<nblocks, 256, 0, stream>>>(desc1, desc2, vis, neigh, negpart);
    k_final<<<1, 256, 0, stream>>>(posim, matchm, negpart, out);
}

// Round 2
// 85.785 us; speedup vs baseline: 2.1966x; 2.1966x over previous
//
#include <hip/hip_runtime.h>
#include <math.h>

#define GS 8
#define HC 60
#define WC 80
#define NN 4800      // HC*WC
#define CC 64
#define BB 2
#define HIMG 480
#define WIMG 640
#define EPSF 1e-8f
#define CS 16        // column-split groups (interleaved 64-col tiles)
#define NTILES 75    // 4800 / 64
#define BIGF 1e30f

typedef __attribute__((ext_vector_type(8))) short short8v;  // 8 bf16 = 4 VGPR
typedef __attribute__((ext_vector_type(4))) float f32x4;

__device__ __forceinline__ unsigned short f2bf(float f) {
    unsigned u = __float_as_uint(f);
    u += 0x7FFFu + ((u >> 16) & 1u);      // RNE
    return (unsigned short)(u >> 16);
}

// ---------------- convert desc1/desc2 fp32 [b][ch][cell] -> bf16 [b][cell][ch] ----------------
__global__ void k_cvt(const float* __restrict__ desc1, const float* __restrict__ desc2,
                      unsigned short* __restrict__ d1bf, unsigned short* __restrict__ d2bf)
{
    __shared__ unsigned short tile[CC][65];   // [ch][cell_local], pad for banks
    int bid = blockIdx.x;                     // 2 arrays * BB * 75 tiles = 300
    int arr = bid / (BB * NTILES);
    int rem = bid % (BB * NTILES);
    int b = rem / NTILES;
    int t = rem % NTILES;
    int c0 = t * 64;
    const float* in = arr ? desc2 : desc1;
    unsigned short* out = arr ? d2bf : d1bf;
    int tid = threadIdx.x;
    int w = tid >> 6, l = tid & 63;

    #pragma unroll
    for (int k = 0; k < 16; k++) {
        int ch = k * 4 + w;
        tile[ch][l] = f2bf(in[((size_t)(b * CC + ch)) * NN + c0 + l]);
    }
    __syncthreads();
    #pragma unroll
    for (int k = 0; k < 16; k++) {
        int cell = k * 4 + w;
        out[((size_t)b * NN + c0 + cell) * CC + l] = tile[l][cell];
    }
}

// ---------------- per-cell prep: warp, pos_sim, match, packed top-4 neighbors ----------------
__global__ void k_prep(const float* __restrict__ desc1,
                       const float* __restrict__ desc2,
                       const float* __restrict__ homo12,
                       float* __restrict__ posim,
                       float* __restrict__ matchm,
                       int*   __restrict__ neighpk)
{
    int idx = blockIdx.x * 256 + threadIdx.x;
    if (idx >= BB * NN) return;
    int b = idx / NN, r = idx - b * NN;
    int ci = r / WC, cj = r - ci * WC;
    float x = cj * 8.0f + 3.5f;
    float y = ci * 8.0f + 3.5f;
    const float* h = homo12 + b * 9;
    float qx = h[0]*x + h[1]*y + h[2];
    float qy = h[3]*x + h[4]*y + h[5];
    float qw = h[6]*x + h[7]*y + h[8];
    float wx = qx / (qw + EPSF);
    float wy = qy / (qw + EPSF);

    matchm[idx] = (wy >= 0.0f && wy <= (float)(HIMG-1) &&
                   wx >= 0.0f && wx <= (float)(WIMG-1)) ? 1.0f : 0.0f;

    float dy = (wy - 4.0f + 0.5f) / 8.0f;
    float dx = (wx - 4.0f + 0.5f) / 8.0f;

    float y0f = floorf(dy), x0f = floorf(dx);
    float fy = dy - y0f, fx = dx - x0f;
    float y1f = y0f + 1.0f, x1f = x0f + 1.0f;
    bool v0y = (y0f >= 0.0f && y0f <= (float)(HC-1));
    bool v1y = (y1f >= 0.0f && y1f <= (float)(HC-1));
    bool v0x = (x0f >= 0.0f && x0f <= (float)(WC-1));
    bool v1x = (x1f >= 0.0f && x1f <= (float)(WC-1));
    float w00 = (1.0f-fy)*(1.0f-fx); if (!(v0y && v0x)) w00 = 0.0f;
    float w01 = (1.0f-fy)*fx;        if (!(v0y && v1x)) w01 = 0.0f;
    float w10 = fy*(1.0f-fx);        if (!(v1y && v0x)) w10 = 0.0f;
    float w11 = fy*fx;               if (!(v1y && v1x)) w11 = 0.0f;
    int yc0 = (int)fminf(fmaxf(y0f, 0.0f), (float)(HC-1));
    int yc1 = (int)fminf(fmaxf(y1f, 0.0f), (float)(HC-1));
    int xc0 = (int)fminf(fmaxf(x0f, 0.0f), (float)(WC-1));
    int xc1 = (int)fminf(fmaxf(x1f, 0.0f), (float)(WC-1));
    int o00 = yc0*WC + xc0, o01 = yc0*WC + xc1;
    int o10 = yc1*WC + xc0, o11 = yc1*WC + xc1;

    const float* d2b = desc2 + (size_t)b * CC * NN;
    const float* d1b = desc1 + (size_t)b * CC * NN;
    float s2 = 0.0f, sd = 0.0f;
    for (int ch = 0; ch < CC; ch++) {
        const float* p = d2b + ch * NN;
        float wv = w00*p[o00] + w01*p[o01] + w10*p[o10] + w11*p[o11];
        s2 += wv * wv;
        sd += d1b[ch*NN + r] * wv;
    }
    float dot = sd / (sqrtf(s2) + EPSF);
    posim[idx] = sqrtf(fmaxf(2.0f - 2.0f*dot, EPSF));

    // ---- top-4 nearest grid centers -> packed bbox mask ----
    int i0 = (int)floorf(dy);
    int j0 = (int)floorf(dx);
    int ilo = i0 - 1; if (ilo < 0) ilo = 0; if (ilo > HC-4) ilo = HC-4;
    int jlo = j0 - 1; if (jlo < 0) jlo = 0; if (jlo > WC-4) jlo = WC-4;
    float bd0=3e38f, bd1=3e38f, bd2=3e38f, bd3=3e38f;
    int   id0=0,     id1=0,     id2=0,     id3=0;
    #pragma unroll
    for (int a = 0; a < 4; a++) {
        float cy = (float)(ilo + a) * 8.0f + 3.5f;
        float ddy = wy - cy;
        float ddy2 = ddy * ddy;
        #pragma unroll
        for (int q = 0; q < 4; q++) {
            float cx = (float)(jlo + q) * 8.0f + 3.5f;
            float ddx = wx - cx;
            float dv = ddy2 + ddx * ddx;
            int id = (ilo + a) * WC + (jlo + q);
            if (dv < bd3) {             // strict: lower index wins ties
                bd3 = dv; id3 = id;
                if (bd3 < bd2) { float tf=bd2; bd2=bd3; bd3=tf; int ti=id2; id2=id3; id3=ti; }
                if (bd2 < bd1) { float tf=bd1; bd1=bd2; bd2=tf; int ti=id1; id1=id2; id2=ti; }
                if (bd1 < bd0) { float tf=bd0; bd0=bd1; bd1=tf; int ti=id0; id0=id1; id1=ti; }
            }
        }
    }
    int base = ilo * WC + jlo;
    int mask = 0;
    {
        int d, ri, rj;
        d = id0 - base; ri = d / WC; rj = d - ri * WC; mask |= 1 << (ri*4+rj);
        d = id1 - base; ri = d / WC; rj = d - ri * WC; mask |= 1 << (ri*4+rj);
        d = id2 - base; ri = d / WC; rj = d - ri * WC; mask |= 1 << (ri*4+rj);
        d = id3 - base; ri = d / WC; rj = d - ri * WC; mask |= 1 << (ri*4+rj);
    }
    neighpk[idx] = mask | (ilo << 16) | (jlo << 24);
}

// ---------------- visibility mask per cell ----------------
__global__ void k_vis(const float* __restrict__ homo21, float* __restrict__ vism)
{
    int idx = blockIdx.x * 256 + threadIdx.x;
    if (idx >= BB * NN) return;
    int b = idx / NN, r = idx - b * NN;
    int ci = r / WC, cj = r - ci * WC;
    const float* h = homo21 + b * 9;
    bool all = true;
    for (int di = 0; di < GS && all; di++) {
        float y = (float)(ci * 8 + di);
        for (int dj = 0; dj < GS; dj++) {
            float x = (float)(cj * 8 + dj);
            float qx = h[0]*x + h[1]*y + h[2];
            float qy = h[3]*x + h[4]*y + h[5];
            float qw = h[6]*x + h[7]*y + h[8];
            float px = qx / (qw + EPSF);
            float py = qy / (qw + EPSF);
            float y0 = floorf(py), x0 = floorf(px);
            float ty = py - y0,   tx = px - x0;
            float fyv = ((y0 >= 0.0f && y0 <= (float)(HIMG-1)) ? (1.0f-ty) : 0.0f)
                      + ((y0+1.0f >= 0.0f && y0+1.0f <= (float)(HIMG-1)) ? ty : 0.0f);
            float fxv = ((x0 >= 0.0f && x0 <= (float)(WIMG-1)) ? (1.0f-tx) : 0.0f)
                      + ((x0+1.0f >= 0.0f && x0+1.0f <= (float)(WIMG-1)) ? tx : 0.0f);
            if (!(fyv > 0.0f && fxv > 0.0f)) { all = false; break; }
        }
    }
    vism[idx] = all ? 1.0f : 0.0f;
}

// ---------------- MFMA fused GEMM + class-max min-reduction ----------------
__global__ __launch_bounds__(256) void k_negmin(
    const unsigned short* __restrict__ d1bf, const unsigned short* __restrict__ d2bf,
    const float* __restrict__ vism, const int* __restrict__ neighpk,
    float* __restrict__ negpart)
{
    int bid = blockIdx.x;                 // BB * 150 * 4 = 1200
    int b   = bid / 600;
    int rem = bid % 600;
    int rb  = rem >> 2;
    int sg  = rem & 3;
    int tid = threadIdx.x;
    int wv  = tid >> 6;
    int lane = tid & 63;
    int s = sg * 4 + wv;                  // col-split 0..15
    int r0 = rb * 32;
    int l15 = lane & 15;
    int lg  = lane >> 4;                  // 0..3

    // A fragments: rows r0..r0+31, K=64 (2 row frags x 2 K frags)
    short8v afr[2][2];
    #pragma unroll
    for (int rf = 0; rf < 2; rf++)
        #pragma unroll
        for (int kf = 0; kf < 2; kf++)
            afr[rf][kf] = *(const short8v*)(d1bf +
                ((size_t)(b * NN + r0 + rf * 16 + l15) * CC + kf * 32 + lg * 8));

    // packed neighbor info for the 8 rows this lane owns (slot = rf*4+reg)
    int pk[8];
    int lmin = 0x7FFFFFFF, lmax = -1;
    #pragma unroll
    for (int slot = 0; slot < 8; slot++) {
        int row = r0 + (slot >> 2) * 16 + lg * 4 + (slot & 3);
        int p = neighpk[b * NN + row];
        pk[slot] = p;
        int ilo = (p >> 16) & 0xFF, jlo = (p >> 24) & 0xFF;
        int idm = ilo * WC + jlo;
        lmin = min(lmin, idm);
        lmax = max(lmax, idm + 3 * WC + 3);
    }
    #pragma unroll
    for (int off = 1; off < 64; off <<= 1) {
        lmin = min(lmin, __shfl_xor(lmin, off));
        lmax = max(lmax, __shfl_xor(lmax, off));
    }

    float m0[8], m5[8], m10[8];
    #pragma unroll
    for (int i = 0; i < 8; i++) { m0[i] = -BIGF; m5[i] = -BIGF; m10[i] = -BIGF; }

    for (int t = s; t < NTILES; t += CS) {
        int tb = t * 64;
        // B fragments: cols tb..tb+63 (4 col frags x 2 K frags)
        short8v bfr[4][2];
        #pragma unroll
        for (int cf = 0; cf < 4; cf++)
            #pragma unroll
            for (int kf = 0; kf < 2; kf++)
                bfr[cf][kf] = *(const short8v*)(d2bf +
                    ((size_t)(b * NN + tb + cf * 16 + l15) * CC + kf * 32 + lg * 8));

        f32x4 acc[2][4] = {};
        #pragma unroll
        for (int kf = 0; kf < 2; kf++)
            #pragma unroll
            for (int rf = 0; rf < 2; rf++)
                #pragma unroll
                for (int cf = 0; cf < 4; cf++)
                    acc[rf][cf] = __builtin_amdgcn_mfma_f32_16x16x32_bf16(
                        afr[rf][kf], bfr[cf][kf], acc[rf][cf], 0, 0, 0);

        // per-column visibility penalties (col = tb + cf*16 + l15)
        float a0[4], a5[4]; float vv[4];
        #pragma unroll
        for (int cf = 0; cf < 4; cf++) {
            float v = vism[b * NN + tb + cf * 16 + l15];
            vv[cf] = v;
            a0[cf] = (v - 1.0f) * BIGF;   // 0 if visible, -BIG if not
            a5[cf] = -v * BIGF;           // -BIG if visible, 0 if not
        }

        bool slow = (tb + 63 >= lmin) && (tb <= lmax);
        if (!slow) {
            #pragma unroll
            for (int rf = 0; rf < 2; rf++)
                #pragma unroll
                for (int cf = 0; cf < 4; cf++)
                    #pragma unroll
                    for (int reg = 0; reg < 4; reg++) {
                        float sv = acc[rf][cf][reg];
                        int slot = rf * 4 + reg;
                        m0[slot] = fmaxf(m0[slot], sv + a0[cf]);
                        m5[slot] = fmaxf(m5[slot], sv + a5[cf]);
                    }
        } else {
            int gi[4], gj[4];
            #pragma unroll
            for (int cf = 0; cf < 4; cf++) {
                int c = tb + cf * 16 + l15;
                gi[cf] = c / WC;
                gj[cf] = c - gi[cf] * WC;
            }
            #pragma unroll
            for (int rf = 0; rf < 2; rf++)
                #pragma unroll
                for (int reg = 0; reg < 4; reg++) {
                    int slot = rf * 4 + reg;
                    int p = pk[slot];
                    int msk = p & 0xFFFF;
                    int ilo = (p >> 16) & 0xFF, jlo = (p >> 24) & 0xFF;
                    #pragma unroll
                    for (int cf = 0; cf < 4; cf++) {
                        unsigned ri = (unsigned)(gi[cf] - ilo);
                        unsigned rj = (unsigned)(gj[cf] - jlo);
                        unsigned bidx = (ri < 4u && rj < 4u) ? (ri * 4u + rj) : 16u;
                        bool nb = (msk >> bidx) & 1;
                        bool visb = vv[cf] > 0.5f;
                        float sv = acc[rf][cf][reg];
                        float c0v  = (visb && !nb) ? sv : -BIGF;
                        float c5v  = (visb == nb)  ? sv : -BIGF;
                        float c10v = (!visb && nb) ? sv : -BIGF;
                        m0[slot]  = fmaxf(m0[slot],  c0v);
                        m5[slot]  = fmaxf(m5[slot],  c5v);
                        m10[slot] = fmaxf(m10[slot], c10v);
                    }
                }
        }
    }

    // finalize: per-slot min over classes, then reduce across the 16 lanes sharing the row
    #pragma unroll
    for (int slot = 0; slot < 8; slot++) {
        float v0  = sqrtf(fmaxf(2.0f - 2.0f * m0[slot],  EPSF));
        float v5  = sqrtf(fmaxf(2.0f - 2.0f * m5[slot],  EPSF)) + 5.0f;
        float v10 = sqrtf(fmaxf(2.0f - 2.0f * m10[slot], EPSF)) + 10.0f;
        float res = fminf(v0, fminf(v5, v10));
        #pragma unroll
        for (int off = 1; off < 16; off <<= 1)
            res = fminf(res, __shfl_xor(res, off));
        if (l15 == 0) {
            int row = r0 + (slot >> 2) * 16 + lg * 4 + (slot & 3);
            negpart[(size_t)(b * NN + row) * CS + s] = res;
        }
    }
}

// ---------------- per-row loss + per-block partial sums ----------------
__global__ void k_loss(const float* __restrict__ posim, const float* __restrict__ matchm,
                       const float* __restrict__ negpart, float* __restrict__ bpart)
{
    __shared__ float sn[256], sdn[256];
    int tid = threadIdx.x;
    int idx = blockIdx.x * 256 + tid;
    float num = 0.0f, den = 0.0f;
    if (idx < BB * NN) {
        const float* np = negpart + (size_t)idx * CS;
        float neg = np[0];
        #pragma unroll
        for (int j = 1; j < CS; j++) neg = fminf(neg, np[j]);
        float l = fmaxf(posim[idx] - neg + 1.0f, 0.0f);
        float mm = matchm[idx];
        num = l * l * mm;
        den = mm;
    }
    sn[tid] = num; sdn[tid] = den;
    __syncthreads();
    for (int st = 128; st > 0; st >>= 1) {
        if (tid < st) { sn[tid] += sn[tid + st]; sdn[tid] += sdn[tid + st]; }
        __syncthreads();
    }
    if (tid == 0) { bpart[blockIdx.x * 2] = sn[0]; bpart[blockIdx.x * 2 + 1] = sdn[0]; }
}

__global__ void k_sum(const float* __restrict__ bpart, int nb, float* __restrict__ out)
{
    int t = threadIdx.x;
    float num = 0.0f, den = 0.0f;
    if (t < nb) { num = bpart[t * 2]; den = bpart[t * 2 + 1]; }
    #pragma unroll
    for (int off = 1; off < 64; off <<= 1) {
        num += __shfl_xor(num, off);
        den += __shfl_xor(den, off);
    }
    if (t == 0) out[0] = num / den;
}

extern "C" void kernel_launch(void* const* d_in, const int* in_sizes, int n_in,
                              void* d_out, int out_size, void* d_ws, size_t ws_size,
                              hipStream_t stream)
{
    const float* desc1  = (const float*)d_in[2];
    const float* desc2  = (const float*)d_in[3];
    const float* homo12 = (const float*)d_in[4];
    const float* homo21 = (const float*)d_in[5];
    float* out = (float*)d_out;

    float* vis     = (float*)d_ws;                  // 9600
    float* posim   = vis + BB * NN;                 // 9600
    float* matchm  = posim + BB * NN;               // 9600
    float* negpart = matchm + BB * NN;              // 9600*16
    int*   neighpk = (int*)(negpart + BB * NN * CS);// 9600
    float* bpart   = (float*)(neighpk + BB * NN);   // 128
    unsigned short* d1bf = (unsigned short*)(bpart + 128);
    unsigned short* d2bf = d1bf + (size_t)BB * NN * CC;

    int nitems = BB * NN;
    int nb = (nitems + 255) / 256;                  // 38

    k_cvt<<<2 * BB * NTILES, 256, 0, stream>>>(desc1, desc2, d1bf, d2bf);
    k_vis<<<nb, 256, 0, stream>>>(homo21, vis);
    k_prep<<<nb, 256, 0, stream>>>(desc1, desc2, homo12, posim, matchm, neighpk);
    k_negmin<<<BB * 150 * 4, 256, 0, stream>>>(d1bf, d2bf, vis, neighpk, negpart);
    k_loss<<<nb, 256, 0, stream>>>(posim, matchm, negpart, bpart);
    k_sum<<<1, 64, 0, stream>>>(bpart, nb, out);
}

// Round 3
// 77.525 us; speedup vs baseline: 2.4306x; 1.1065x over previous
//
#include <hip/hip_runtime.h>
#include <math.h>

#define GS 8
#define HC 60
#define WC 80
#define NN 4800      // HC*WC
#define CC 64
#define BB 2
#define HIMG 480
#define WIMG 640
#define EPSF 1e-8f
#define NTILES 75    // 4800 / 64
#define TG 8         // tile groups (column splits)
#define RPB 64       // rows per block
#define BIGF 1e30f

typedef __attribute__((ext_vector_type(8))) short short8v;  // 8 bf16 = 4 VGPR
typedef __attribute__((ext_vector_type(4))) float f32x4;

__device__ __forceinline__ unsigned short f2bf(float f) {
    unsigned u = __float_as_uint(f);
    u += 0x7FFFu + ((u >> 16) & 1u);      // RNE
    return (unsigned short)(u >> 16);
}

// ============ fused: bf16 convert/transpose (blocks 0..299) | prep+vis (blocks 300..337) ============
__global__ __launch_bounds__(256) void k_pre(
    const float* __restrict__ desc1, const float* __restrict__ desc2,
    const float* __restrict__ homo12, const float* __restrict__ homo21,
    unsigned short* __restrict__ d1bf, unsigned short* __restrict__ d2bf,
    float* __restrict__ posim, float* __restrict__ matchm,
    float* __restrict__ vism, int* __restrict__ neighpk)
{
    __shared__ unsigned short tile[CC][65];
    int bid = blockIdx.x;
    int tid = threadIdx.x;

    if (bid < 2 * BB * NTILES) {
        // ---- convert fp32 [b][ch][cell] -> bf16 [b][cell][ch] ----
        int arr = bid / (BB * NTILES);
        int rem = bid % (BB * NTILES);
        int b = rem / NTILES;
        int t = rem % NTILES;
        int c0 = t * 64;
        const float* in = arr ? desc2 : desc1;
        unsigned short* out = arr ? d2bf : d1bf;
        int w = tid >> 6, l = tid & 63;
        #pragma unroll
        for (int k = 0; k < 16; k++) {
            int ch = k * 4 + w;
            tile[ch][l] = f2bf(in[((size_t)(b * CC + ch)) * NN + c0 + l]);
        }
        __syncthreads();
        #pragma unroll
        for (int k = 0; k < 16; k++) {
            int cell = k * 4 + w;
            out[((size_t)b * NN + c0 + cell) * CC + l] = tile[l][cell];
        }
        return;
    }

    int idx = (bid - 2 * BB * NTILES) * 256 + tid;
    if (idx >= BB * NN) return;
    int b = idx / NN, r = idx - b * NN;
    int ci = r / WC, cj = r - ci * WC;

    // ---- warp cell center by homo12 ----
    {
        float x = cj * 8.0f + 3.5f;
        float y = ci * 8.0f + 3.5f;
        const float* h = homo12 + b * 9;
        float qx = h[0]*x + h[1]*y + h[2];
        float qy = h[3]*x + h[4]*y + h[5];
        float qw = h[6]*x + h[7]*y + h[8];
        float wx = qx / (qw + EPSF);
        float wy = qy / (qw + EPSF);

        matchm[idx] = (wy >= 0.0f && wy <= (float)(HIMG-1) &&
                       wx >= 0.0f && wx <= (float)(WIMG-1)) ? 1.0f : 0.0f;

        float dy = (wy - 4.0f + 0.5f) / 8.0f;
        float dx = (wx - 4.0f + 0.5f) / 8.0f;

        float y0f = floorf(dy), x0f = floorf(dx);
        float fy = dy - y0f, fx = dx - x0f;
        float y1f = y0f + 1.0f, x1f = x0f + 1.0f;
        bool v0y = (y0f >= 0.0f && y0f <= (float)(HC-1));
        bool v1y = (y1f >= 0.0f && y1f <= (float)(HC-1));
        bool v0x = (x0f >= 0.0f && x0f <= (float)(WC-1));
        bool v1x = (x1f >= 0.0f && x1f <= (float)(WC-1));
        float w00 = (1.0f-fy)*(1.0f-fx); if (!(v0y && v0x)) w00 = 0.0f;
        float w01 = (1.0f-fy)*fx;        if (!(v0y && v1x)) w01 = 0.0f;
        float w10 = fy*(1.0f-fx);        if (!(v1y && v0x)) w10 = 0.0f;
        float w11 = fy*fx;               if (!(v1y && v1x)) w11 = 0.0f;
        int yc0 = (int)fminf(fmaxf(y0f, 0.0f), (float)(HC-1));
        int yc1 = (int)fminf(fmaxf(y1f, 0.0f), (float)(HC-1));
        int xc0 = (int)fminf(fmaxf(x0f, 0.0f), (float)(WC-1));
        int xc1 = (int)fminf(fmaxf(x1f, 0.0f), (float)(WC-1));
        int o00 = yc0*WC + xc0, o01 = yc0*WC + xc1;
        int o10 = yc1*WC + xc0, o11 = yc1*WC + xc1;

        const float* d2b = desc2 + (size_t)b * CC * NN;
        const float* d1b = desc1 + (size_t)b * CC * NN;
        float s2 = 0.0f, sd = 0.0f;
        for (int ch = 0; ch < CC; ch++) {
            const float* p = d2b + ch * NN;
            float wv = w00*p[o00] + w01*p[o01] + w10*p[o10] + w11*p[o11];
            s2 += wv * wv;
            sd += d1b[ch*NN + r] * wv;
        }
        float dot = sd / (sqrtf(s2) + EPSF);
        posim[idx] = sqrtf(fmaxf(2.0f - 2.0f*dot, EPSF));

        // ---- top-4 nearest grid centers -> packed bbox mask ----
        int i0 = (int)floorf(dy);
        int j0 = (int)floorf(dx);
        int ilo = i0 - 1; if (ilo < 0) ilo = 0; if (ilo > HC-4) ilo = HC-4;
        int jlo = j0 - 1; if (jlo < 0) jlo = 0; if (jlo > WC-4) jlo = WC-4;
        float bd0=3e38f, bd1=3e38f, bd2=3e38f, bd3=3e38f;
        int   id0=0,     id1=0,     id2=0,     id3=0;
        #pragma unroll
        for (int a = 0; a < 4; a++) {
            float cy = (float)(ilo + a) * 8.0f + 3.5f;
            float ddy = wy - cy;
            float ddy2 = ddy * ddy;
            #pragma unroll
            for (int q = 0; q < 4; q++) {
                float cx = (float)(jlo + q) * 8.0f + 3.5f;
                float ddx = wx - cx;
                float dv = ddy2 + ddx * ddx;
                int id = (ilo + a) * WC + (jlo + q);
                if (dv < bd3) {             // strict: lower index wins ties
                    bd3 = dv; id3 = id;
                    if (bd3 < bd2) { float tf=bd2; bd2=bd3; bd3=tf; int ti=id2; id2=id3; id3=ti; }
                    if (bd2 < bd1) { float tf=bd1; bd1=bd2; bd2=tf; int ti=id1; id1=id2; id2=ti; }
                    if (bd1 < bd0) { float tf=bd0; bd0=bd1; bd1=tf; int ti=id0; id0=id1; id1=ti; }
                }
            }
        }
        int base = ilo * WC + jlo;
        int mask = 0;
        {
            int d, ri, rj;
            d = id0 - base; ri = d / WC; rj = d - ri * WC; mask |= 1 << (ri*4+rj);
            d = id1 - base; ri = d / WC; rj = d - ri * WC; mask |= 1 << (ri*4+rj);
            d = id2 - base; ri = d / WC; rj = d - ri * WC; mask |= 1 << (ri*4+rj);
            d = id3 - base; ri = d / WC; rj = d - ri * WC; mask |= 1 << (ri*4+rj);
        }
        neighpk[idx] = mask | (ilo << 16) | (jlo << 24);
    }

    // ---- visibility: all 64 pixels of the cell visible under homo21 ----
    {
        const float* h = homo21 + b * 9;
        bool all = true;
        for (int di = 0; di < GS && all; di++) {
            float y = (float)(ci * 8 + di);
            for (int dj = 0; dj < GS; dj++) {
                float x = (float)(cj * 8 + dj);
                float qx = h[0]*x + h[1]*y + h[2];
                float qy = h[3]*x + h[4]*y + h[5];
                float qw = h[6]*x + h[7]*y + h[8];
                float px = qx / (qw + EPSF);
                float py = qy / (qw + EPSF);
                float y0 = floorf(py), x0 = floorf(px);
                float ty = py - y0,   tx = px - x0;
                float fyv = ((y0 >= 0.0f && y0 <= (float)(HIMG-1)) ? (1.0f-ty) : 0.0f)
                          + ((y0+1.0f >= 0.0f && y0+1.0f <= (float)(HIMG-1)) ? ty : 0.0f);
                float fxv = ((x0 >= 0.0f && x0 <= (float)(WIMG-1)) ? (1.0f-tx) : 0.0f)
                          + ((x0+1.0f >= 0.0f && x0+1.0f <= (float)(WIMG-1)) ? tx : 0.0f);
                if (!(fyv > 0.0f && fxv > 0.0f)) { all = false; break; }
            }
        }
        vism[idx] = all ? 1.0f : 0.0f;
    }
}

// ============ MFMA fused GEMM + class-max min-reduction ============
// block = 64 rows x (tiles t = tg, tg+8, ...); 4 waves each own a 16-col slice.
__global__ __launch_bounds__(256) void k_negmin(
    const unsigned short* __restrict__ d1bf, const unsigned short* __restrict__ d2bf,
    const float* __restrict__ vism, const int* __restrict__ neighpk,
    float* __restrict__ negpart)
{
    __shared__ float sres[4 * RPB];

    int bid = blockIdx.x;                 // BB * 75 * TG = 1200
    int b   = bid / (75 * TG);
    int rem = bid % (75 * TG);
    int rb  = rem / TG;
    int tg  = rem % TG;
    int tid = threadIdx.x;
    int w   = tid >> 6;
    int lane = tid & 63;
    int l15 = lane & 15;
    int lg  = lane >> 4;
    int r0  = rb * RPB;

    const unsigned short* d1b = d1bf + (size_t)b * NN * CC;
    const unsigned short* d2b = d2bf + (size_t)b * NN * CC;

    // A fragments: rows r0..r0+63 (4 row frags x 2 K frags)
    short8v afr[4][2];
    #pragma unroll
    for (int rf = 0; rf < 4; rf++)
        #pragma unroll
        for (int kf = 0; kf < 2; kf++)
            afr[rf][kf] = *(const short8v*)(d1b +
                ((size_t)(r0 + rf * 16 + l15) * CC + kf * 32 + lg * 8));

    // wave-level neighbor bbox (conservative linear range)
    int lmin = 0x7FFFFFFF, lmax = -1;
    #pragma unroll
    for (int slot = 0; slot < 16; slot++) {
        int row = r0 + (slot >> 2) * 16 + lg * 4 + (slot & 3);
        int p = neighpk[b * NN + row];
        int ilo = (p >> 16) & 0xFF, jlo = (p >> 24) & 0xFF;
        int idm = ilo * WC + jlo;
        lmin = min(lmin, idm);
        lmax = max(lmax, idm + 3 * WC + 3);
    }
    #pragma unroll
    for (int off = 1; off < 64; off <<= 1) {
        lmin = min(lmin, __shfl_xor(lmin, off));
        lmax = max(lmax, __shfl_xor(lmax, off));
    }

    float m0[16], m5[16];
    #pragma unroll
    for (int i = 0; i < 16; i++) { m0[i] = -BIGF; m5[i] = -BIGF; }

    int c = tg * 64 + w * 16 + l15;       // this lane's column for tile t=tg
    short8v bfr[2], bfrn[2];
    float vv, vvn;
    bfr[0] = *(const short8v*)(d2b + (size_t)c * CC + lg * 8);
    bfr[1] = *(const short8v*)(d2b + (size_t)c * CC + 32 + lg * 8);
    vv = vism[b * NN + c];

    for (int t = tg; t < NTILES; t += TG) {
        int cn = c + TG * 64;
        if (t + TG < NTILES) {            // prefetch next tile (reg-staged)
            bfrn[0] = *(const short8v*)(d2b + (size_t)cn * CC + lg * 8);
            bfrn[1] = *(const short8v*)(d2b + (size_t)cn * CC + 32 + lg * 8);
            vvn = vism[b * NN + cn];
        }

        f32x4 acc[4] = {};
        #pragma unroll
        for (int kf = 0; kf < 2; kf++)
            #pragma unroll
            for (int rf = 0; rf < 4; rf++)
                acc[rf] = __builtin_amdgcn_mfma_f32_16x16x32_bf16(
                    afr[rf][kf], bfr[kf], acc[rf], 0, 0, 0);

        int tb = t * 64;
        bool slow = (tb + 63 >= lmin) && (tb <= lmax);
        bool visb = vv > 0.5f;
        if (!slow) {
            // no neighbor columns in this tile for any row of this wave
            if (visb) {
                #pragma unroll
                for (int slot = 0; slot < 16; slot++)
                    m0[slot] = fmaxf(m0[slot], acc[slot >> 2][slot & 3]);
            } else {
                #pragma unroll
                for (int slot = 0; slot < 16; slot++)
                    m5[slot] = fmaxf(m5[slot], acc[slot >> 2][slot & 3]);
            }
        } else {
            int gi = c / WC, gj = c - (c / WC) * WC;
            #pragma unroll
            for (int slot = 0; slot < 16; slot++) {
                int row = r0 + (slot >> 2) * 16 + lg * 4 + (slot & 3);
                int p = neighpk[b * NN + row];
                int msk = p & 0xFFFF;
                int ilo = (p >> 16) & 0xFF, jlo = (p >> 24) & 0xFF;
                unsigned ri = (unsigned)(gi - ilo);
                unsigned rj = (unsigned)(gj - jlo);
                unsigned bidx = (ri < 4u && rj < 4u) ? (ri * 4u + rj) : 16u;
                bool nb = (msk >> bidx) & 1;
                float sv = acc[slot >> 2][slot & 3];
                if (visb) {
                    m0[slot] = fmaxf(m0[slot], nb ? -BIGF : sv);
                    m5[slot] = fmaxf(m5[slot], nb ? sv : -BIGF);
                } else {
                    // class10 (invisible neighbor) provably never the min: skip
                    if (!nb) m5[slot] = fmaxf(m5[slot], sv);
                }
            }
        }

        bfr[0] = bfrn[0]; bfr[1] = bfrn[1]; vv = vvn; c = cn;
    }

    // finalize: min over classes, reduce across the 16 lanes sharing each row
    #pragma unroll
    for (int slot = 0; slot < 16; slot++) {
        float v0 = sqrtf(fmaxf(2.0f - 2.0f * m0[slot], EPSF));
        float v5 = sqrtf(fmaxf(2.0f - 2.0f * m5[slot], EPSF)) + 5.0f;
        float res = fminf(v0, v5);
        #pragma unroll
        for (int off = 1; off < 16; off <<= 1)
            res = fminf(res, __shfl_xor(res, off));
        if (l15 == 0)
            sres[w * RPB + (slot >> 2) * 16 + lg * 4 + (slot & 3)] = res;
    }
    __syncthreads();
    if (tid < RPB) {
        float m = fminf(fminf(sres[tid], sres[RPB + tid]),
                        fminf(sres[2 * RPB + tid], sres[3 * RPB + tid]));
        negpart[(size_t)(b * NN + r0 + tid) * TG + tg] = m;
    }
}

// ============ final loss (single block) ============
__global__ __launch_bounds__(1024) void k_loss(
    const float* __restrict__ posim, const float* __restrict__ matchm,
    const float* __restrict__ negpart, float* __restrict__ out)
{
    __shared__ float sn[1024], sd[1024];
    int tid = threadIdx.x;
    float num = 0.0f, den = 0.0f;
    for (int i = tid; i < BB * NN; i += 1024) {
        const float4* np = (const float4*)(negpart + (size_t)i * TG);
        float4 a = np[0], bq = np[1];
        float neg = fminf(fminf(fminf(a.x, a.y), fminf(a.z, a.w)),
                          fminf(fminf(bq.x, bq.y), fminf(bq.z, bq.w)));
        float l = fmaxf(posim[i] - neg + 1.0f, 0.0f);
        float mm = matchm[i];
        num += l * l * mm;
        den += mm;
    }
    sn[tid] = num; sd[tid] = den;
    __syncthreads();
    for (int s = 512; s > 0; s >>= 1) {
        if (tid < s) { sn[tid] += sn[tid + s]; sd[tid] += sd[tid + s]; }
        __syncthreads();
    }
    if (tid == 0) out[0] = sn[0] / sd[0];
}

extern "C" void kernel_launch(void* const* d_in, const int* in_sizes, int n_in,
                              void* d_out, int out_size, void* d_ws, size_t ws_size,
                              hipStream_t stream)
{
    const float* desc1  = (const float*)d_in[2];
    const float* desc2  = (const float*)d_in[3];
    const float* homo12 = (const float*)d_in[4];
    const float* homo21 = (const float*)d_in[5];
    float* out = (float*)d_out;

    float* vis     = (float*)d_ws;                    // 9600
    float* posim   = vis + BB * NN;                   // 9600
    float* matchm  = posim + BB * NN;                 // 9600
    int*   neighpk = (int*)(matchm + BB * NN);        // 9600
    float* negpart = (float*)(neighpk + BB * NN);     // 9600 * 8
    unsigned short* d1bf = (unsigned short*)(negpart + BB * NN * TG);
    unsigned short* d2bf = d1bf + (size_t)BB * NN * CC;

    int nb_pre = 2 * BB * NTILES + (BB * NN + 255) / 256;   // 300 + 38
    k_pre<<<nb_pre, 256, 0, stream>>>(desc1, desc2, homo12, homo21,
                                      d1bf, d2bf, posim, matchm, vis, neighpk);
    k_negmin<<<BB * 75 * TG, 256, 0, stream>>>(d1bf, d2bf, vis, neighpk, negpart);
    k_loss<<<1, 1024, 0, stream>>>(posim, matchm, negpart, out);
}

// Round 4
// 57.274 us; speedup vs baseline: 3.2900x; 1.3536x over previous
//
#include <hip/hip_runtime.h>
#include <math.h>

#define GS 8
#define HC 60
#define WC 80
#define NN 4800      // HC*WC
#define CC 64
#define BB 2
#define HIMG 480
#define WIMG 640
#define EPSF 1e-8f
#define NTILES 75    // 4800 / 64
#define BIGF 1e30f

typedef __attribute__((ext_vector_type(8))) short short8v;  // 8 bf16 = 4 VGPR
typedef __attribute__((ext_vector_type(4))) float f32x4;

__device__ __forceinline__ unsigned short f2bf(float f) {
    unsigned u = __float_as_uint(f);
    u += 0x7FFFu + ((u >> 16) & 1u);      // RNE
    return (unsigned short)(u >> 16);
}

// ============ k_pre: cvt (blocks 0..299) | per-cell wave prep (blocks 300..2699) ============
__global__ __launch_bounds__(256) void k_pre(
    const float* __restrict__ desc1, const float* __restrict__ desc2,
    const float* __restrict__ homo12, const float* __restrict__ homo21,
    unsigned short* __restrict__ d1bf, unsigned short* __restrict__ d2bf,
    float* __restrict__ posim, float* __restrict__ matchm,
    float* __restrict__ vism, int* __restrict__ neighpk,
    unsigned int* __restrict__ negbits)
{
    __shared__ unsigned short tile[CC][65];
    int bid = blockIdx.x;
    int tid = threadIdx.x;

    if (bid < 2 * BB * NTILES) {
        // ---- convert fp32 [b][ch][cell] -> bf16 [b][cell][ch] ----
        int arr = bid / (BB * NTILES);
        int rem = bid % (BB * NTILES);
        int b = rem / NTILES;
        int t = rem % NTILES;
        int c0 = t * 64;
        const float* in = arr ? desc2 : desc1;
        unsigned short* out = arr ? d2bf : d1bf;
        int w = tid >> 6, l = tid & 63;
        #pragma unroll
        for (int k = 0; k < 16; k++) {
            int ch = k * 4 + w;
            tile[ch][l] = f2bf(in[((size_t)(b * CC + ch)) * NN + c0 + l]);
        }
        __syncthreads();
        #pragma unroll
        for (int k = 0; k < 16; k++) {
            int cell = k * 4 + w;
            out[((size_t)b * NN + c0 + cell) * CC + l] = tile[l][cell];
        }
        return;
    }

    // ---- per-cell: one wave per cell ----
    int sub = bid - 2 * BB * NTILES;      // 0..2399
    int wv = tid >> 6, lane = tid & 63;
    int idx = sub * 4 + wv;               // 0..9599
    int b = idx / NN, r = idx - b * NN;
    int ci = r / WC, cj = r - ci * WC;

    // visibility: lane = pixel (di,dj) of the 8x8 cell
    {
        const float* h = homo21 + b * 9;
        int di = lane >> 3, dj = lane & 7;
        float y = (float)(ci * 8 + di);
        float x = (float)(cj * 8 + dj);
        float qx = h[0]*x + h[1]*y + h[2];
        float qy = h[3]*x + h[4]*y + h[5];
        float qw = h[6]*x + h[7]*y + h[8];
        float px = qx / (qw + EPSF);
        float py = qy / (qw + EPSF);
        float y0 = floorf(py), x0 = floorf(px);
        float ty = py - y0,   tx = px - x0;
        float fyv = ((y0 >= 0.0f && y0 <= (float)(HIMG-1)) ? (1.0f-ty) : 0.0f)
                  + ((y0+1.0f >= 0.0f && y0+1.0f <= (float)(HIMG-1)) ? ty : 0.0f);
        float fxv = ((x0 >= 0.0f && x0 <= (float)(WIMG-1)) ? (1.0f-tx) : 0.0f)
                  + ((x0+1.0f >= 0.0f && x0+1.0f <= (float)(WIMG-1)) ? tx : 0.0f);
        int ok = (fyv > 0.0f && fxv > 0.0f) ? 1 : 0;
        int allv = __all(ok);
        if (lane == 0) vism[idx] = allv ? 1.0f : 0.0f;
    }

    // warp + bilinear setup (all lanes redundantly, uniform)
    const float* h = homo12 + b * 9;
    float xx = cj * 8.0f + 3.5f;
    float yy = ci * 8.0f + 3.5f;
    float qx = h[0]*xx + h[1]*yy + h[2];
    float qy = h[3]*xx + h[4]*yy + h[5];
    float qw = h[6]*xx + h[7]*yy + h[8];
    float wx = qx / (qw + EPSF);
    float wy = qy / (qw + EPSF);
    float dy = (wy - 4.0f + 0.5f) / 8.0f;
    float dx = (wx - 4.0f + 0.5f) / 8.0f;

    float y0f = floorf(dy), x0f = floorf(dx);
    float fy = dy - y0f, fx = dx - x0f;
    float y1f = y0f + 1.0f, x1f = x0f + 1.0f;
    bool v0y = (y0f >= 0.0f && y0f <= (float)(HC-1));
    bool v1y = (y1f >= 0.0f && y1f <= (float)(HC-1));
    bool v0x = (x0f >= 0.0f && x0f <= (float)(WC-1));
    bool v1x = (x1f >= 0.0f && x1f <= (float)(WC-1));
    float w00 = (1.0f-fy)*(1.0f-fx); if (!(v0y && v0x)) w00 = 0.0f;
    float w01 = (1.0f-fy)*fx;        if (!(v0y && v1x)) w01 = 0.0f;
    float w10 = fy*(1.0f-fx);        if (!(v1y && v0x)) w10 = 0.0f;
    float w11 = fy*fx;               if (!(v1y && v1x)) w11 = 0.0f;
    int yc0 = (int)fminf(fmaxf(y0f, 0.0f), (float)(HC-1));
    int yc1 = (int)fminf(fmaxf(y1f, 0.0f), (float)(HC-1));
    int xc0 = (int)fminf(fmaxf(x0f, 0.0f), (float)(WC-1));
    int xc1 = (int)fminf(fmaxf(x1f, 0.0f), (float)(WC-1));
    int o00 = yc0*WC + xc0, o01 = yc0*WC + xc1;
    int o10 = yc1*WC + xc0, o11 = yc1*WC + xc1;

    // lane = channel
    int ch = lane;
    const float* d2b = desc2 + (size_t)b * CC * NN;
    const float* p = d2b + ch * NN;
    float wvl = w00*p[o00] + w01*p[o01] + w10*p[o10] + w11*p[o11];
    float s2 = wvl * wvl;
    float sd = desc1[((size_t)(b * CC + ch)) * NN + r] * wvl;
    #pragma unroll
    for (int off = 1; off < 64; off <<= 1) {
        s2 += __shfl_xor(s2, off);
        sd += __shfl_xor(sd, off);
    }

    if (lane == 0) {
        matchm[idx] = (wy >= 0.0f && wy <= (float)(HIMG-1) &&
                       wx >= 0.0f && wx <= (float)(WIMG-1)) ? 1.0f : 0.0f;
        float dot = sd / (sqrtf(s2) + EPSF);
        posim[idx] = sqrtf(fmaxf(2.0f - 2.0f*dot, EPSF));

        // top-4 nearest grid centers -> packed bbox mask
        int i0 = (int)floorf(dy);
        int j0 = (int)floorf(dx);
        int ilo = i0 - 1; if (ilo < 0) ilo = 0; if (ilo > HC-4) ilo = HC-4;
        int jlo = j0 - 1; if (jlo < 0) jlo = 0; if (jlo > WC-4) jlo = WC-4;
        float bd0=3e38f, bd1=3e38f, bd2=3e38f, bd3=3e38f;
        int   id0=0,     id1=0,     id2=0,     id3=0;
        #pragma unroll
        for (int a = 0; a < 4; a++) {
            float cy = (float)(ilo + a) * 8.0f + 3.5f;
            float ddy = wy - cy;
            float ddy2 = ddy * ddy;
            #pragma unroll
            for (int q = 0; q < 4; q++) {
                float cx = (float)(jlo + q) * 8.0f + 3.5f;
                float ddx = wx - cx;
                float dv = ddy2 + ddx * ddx;
                int id = (ilo + a) * WC + (jlo + q);
                if (dv < bd3) {             // strict: lower index wins ties
                    bd3 = dv; id3 = id;
                    if (bd3 < bd2) { float tf=bd2; bd2=bd3; bd3=tf; int ti=id2; id2=id3; id3=ti; }
                    if (bd2 < bd1) { float tf=bd1; bd1=bd2; bd2=tf; int ti=id1; id1=id2; id2=ti; }
                    if (bd1 < bd0) { float tf=bd0; bd0=bd1; bd1=tf; int ti=id0; id0=id1; id1=ti; }
                }
            }
        }
        int base = ilo * WC + jlo;
        int mask = 0;
        {
            int d, ri, rj;
            d = id0 - base; ri = d / WC; rj = d - ri * WC; mask |= 1 << (ri*4+rj);
            d = id1 - base; ri = d / WC; rj = d - ri * WC; mask |= 1 << (ri*4+rj);
            d = id2 - base; ri = d / WC; rj = d - ri * WC; mask |= 1 << (ri*4+rj);
            d = id3 - base; ri = d / WC; rj = d - ri * WC; mask |= 1 << (ri*4+rj);
        }
        neighpk[idx] = mask | (ilo << 16) | (jlo << 24);
        negbits[idx] = 0x7F800000u;      // +inf
    }
}

// ============ k_negmin: MFMA GEMM + class-max, pipelined pairs, no buffer copies ============

#define LDPAIR(S, J) do {                                                   \
    int jp_ = (J); if (jp_ >= npair) jp_ = npair - 1;                       \
    int cA_ = (tg + 4*jp_)*64 + wcol;                                       \
    const unsigned short* pA_ = d2b + (size_t)cA_ * CC + lg8;               \
    S##a0 = *(const short8v*)(pA_);                                         \
    S##a1 = *(const short8v*)(pA_ + 32);                                    \
    S##va = vism[bNN + cA_];                                                \
    int cB_ = cA_ + 128;                                                    \
    const unsigned short* pB_ = d2b + (size_t)cB_ * CC + lg8;               \
    S##b0 = *(const short8v*)(pB_);                                         \
    S##b1 = *(const short8v*)(pB_ + 32);                                    \
    S##vb = vism[bNN + cB_];                                                \
} while (0)

#define EPI1(X0, X1, TB, VV, SLOW) do {                                     \
    bool visb_ = (VV) > 0.5f;                                               \
    if (!(SLOW)) {                                                          \
        float p0_ = visb_ ? 0.0f : -BIGF;                                   \
        float p5_ = visb_ ? -BIGF : 0.0f;                                   \
        _Pragma("unroll")                                                   \
        for (int g_ = 0; g_ < 4; g_++) {                                    \
            m0[g_]   = fmaxf(m0[g_],   X0[g_] + p0_);                       \
            m5[g_]   = fmaxf(m5[g_],   X0[g_] + p5_);                       \
            m0[4+g_] = fmaxf(m0[4+g_], X1[g_] + p0_);                       \
            m5[4+g_] = fmaxf(m5[4+g_], X1[g_] + p5_);                       \
        }                                                                   \
    } else {                                                                \
        int c_ = (TB) + wcol;                                               \
        int gi_ = c_ / WC; int gj_ = c_ - gi_ * WC;                         \
        _Pragma("unroll")                                                   \
        for (int s_ = 0; s_ < 8; s_++) {                                    \
            int p_ = pk[s_]; int msk_ = p_ & 0xFFFF;                        \
            int ilo_ = (p_ >> 16) & 0xFF, jlo_ = (p_ >> 24) & 0xFF;         \
            unsigned ri_ = (unsigned)(gi_ - ilo_);                          \
            unsigned rj_ = (unsigned)(gj_ - jlo_);                          \
            unsigned bx_ = (ri_ < 4u && rj_ < 4u) ? (ri_*4u + rj_) : 16u;   \
            bool nb_ = (msk_ >> bx_) & 1;                                   \
            float sv_ = (s_ < 4) ? X0[s_ & 3] : X1[s_ & 3];                 \
            if (visb_) {                                                    \
                m0[s_] = fmaxf(m0[s_], nb_ ? -BIGF : sv_);                  \
                m5[s_] = fmaxf(m5[s_], nb_ ? sv_ : -BIGF);                  \
            } else if (!nb_) {                                              \
                m5[s_] = fmaxf(m5[s_], sv_);                                \
            }                                                               \
        }                                                                   \
    }                                                                       \
} while (0)

#define CONS2(S, J) do {                                                    \
    int tbA_ = (tg + 4*(J))*64; int tbB_ = tbA_ + 128;                      \
    f32x4 xA0 = {0,0,0,0}, xA1 = {0,0,0,0};                                 \
    f32x4 xB0 = {0,0,0,0}, xB1 = {0,0,0,0};                                 \
    xA0 = __builtin_amdgcn_mfma_f32_16x16x32_bf16(afr00, S##a0, xA0, 0,0,0);\
    xA0 = __builtin_amdgcn_mfma_f32_16x16x32_bf16(afr01, S##a1, xA0, 0,0,0);\
    xA1 = __builtin_amdgcn_mfma_f32_16x16x32_bf16(afr10, S##a0, xA1, 0,0,0);\
    xA1 = __builtin_amdgcn_mfma_f32_16x16x32_bf16(afr11, S##a1, xA1, 0,0,0);\
    xB0 = __builtin_amdgcn_mfma_f32_16x16x32_bf16(afr00, S##b0, xB0, 0,0,0);\
    xB0 = __builtin_amdgcn_mfma_f32_16x16x32_bf16(afr01, S##b1, xB0, 0,0,0);\
    xB1 = __builtin_amdgcn_mfma_f32_16x16x32_bf16(afr10, S##b0, xB1, 0,0,0);\
    xB1 = __builtin_amdgcn_mfma_f32_16x16x32_bf16(afr11, S##b1, xB1, 0,0,0);\
    bool slowA_ = (tbA_ + 63 >= lmin) && (tbA_ <= lmax);                    \
    bool slowB_ = (tbB_ + 63 >= lmin) && (tbB_ <= lmax);                    \
    if (!slowA_ && !slowB_) {                                               \
        float pA0_ = (S##va > 0.5f) ? 0.0f : -BIGF;                         \
        float pA5_ = (S##va > 0.5f) ? -BIGF : 0.0f;                         \
        float pB0_ = (S##vb > 0.5f) ? 0.0f : -BIGF;                         \
        float pB5_ = (S##vb > 0.5f) ? -BIGF : 0.0f;                         \
        _Pragma("unroll")                                                   \
        for (int g_ = 0; g_ < 4; g_++) {                                    \
            m0[g_]   = fmaxf(m0[g_],   fmaxf(xA0[g_]+pA0_, xB0[g_]+pB0_));  \
            m5[g_]   = fmaxf(m5[g_],   fmaxf(xA0[g_]+pA5_, xB0[g_]+pB5_));  \
            m0[4+g_] = fmaxf(m0[4+g_], fmaxf(xA1[g_]+pA0_, xB1[g_]+pB0_));  \
            m5[4+g_] = fmaxf(m5[4+g_], fmaxf(xA1[g_]+pA5_, xB1[g_]+pB5_));  \
        }                                                                   \
    } else {                                                                \
        EPI1(xA0, xA1, tbA_, S##va, slowA_);                                \
        EPI1(xB0, xB1, tbB_, S##vb, slowB_);                                \
    }                                                                       \
} while (0)

__global__ __launch_bounds__(256) void k_negmin(
    const unsigned short* __restrict__ d1bf, const unsigned short* __restrict__ d2bf,
    const float* __restrict__ vism, const int* __restrict__ neighpk,
    unsigned int* __restrict__ negbits)
{
    __shared__ float sres[4 * 32];

    int bid = blockIdx.x;                 // BB * 150 * 2 = 600
    int b   = bid / 300;
    int rem = bid % 300;
    int rb  = rem >> 1;
    int tg  = rem & 1;
    int tid = threadIdx.x;
    int w   = tid >> 6;
    int lane = tid & 63;
    int l15 = lane & 15, lg = lane >> 4;
    int r0  = rb * 32;
    int wcol = w * 16 + l15;
    int lg8  = lg * 8;
    int bNN  = b * NN;

    const unsigned short* d1b = d1bf + (size_t)bNN * CC;
    const unsigned short* d2b = d2bf + (size_t)bNN * CC;

    short8v afr00 = *(const short8v*)(d1b + (size_t)(r0 + l15) * CC + lg8);
    short8v afr01 = *(const short8v*)(d1b + (size_t)(r0 + l15) * CC + 32 + lg8);
    short8v afr10 = *(const short8v*)(d1b + (size_t)(r0 + 16 + l15) * CC + lg8);
    short8v afr11 = *(const short8v*)(d1b + (size_t)(r0 + 16 + l15) * CC + 32 + lg8);

    int pk[8];
    int lmin = 0x7FFFFFFF, lmax = -1;
    #pragma unroll
    for (int s_ = 0; s_ < 8; s_++) {
        int row = r0 + (s_ >> 2) * 16 + lg * 4 + (s_ & 3);
        int p = neighpk[bNN + row];
        pk[s_] = p;
        int ilo = (p >> 16) & 0xFF, jlo = (p >> 24) & 0xFF;
        int idm = ilo * WC + jlo;
        lmin = min(lmin, idm);
        lmax = max(lmax, idm + 3 * WC + 3);
    }
    #pragma unroll
    for (int off = 1; off < 64; off <<= 1) {
        lmin = min(lmin, __shfl_xor(lmin, off));
        lmax = max(lmax, __shfl_xor(lmax, off));
    }

    float m0[8], m5[8];
    #pragma unroll
    for (int i = 0; i < 8; i++) { m0[i] = -BIGF; m5[i] = -BIGF; }

    int cnt = (NTILES - tg + 1) / 2;      // tg=0: 38, tg=1: 37
    int npair = cnt >> 1;                 // 19 / 18
    int tail = cnt & 1;

    short8v Pa0, Pa1, Pb0, Pb1, Qa0, Qa1, Qb0, Qb1;
    float Pva, Pvb, Qva, Qvb;
    LDPAIR(P, 0);
    LDPAIR(Q, 1);

    int j = 0;
    for (; j + 2 < npair; j += 2) {
        CONS2(P, j);     LDPAIR(P, j + 2);
        CONS2(Q, j + 1); LDPAIR(Q, j + 3);
    }

    // issue tail-tile load early so it overlaps the leftover consumes
    short8v Ta0, Ta1; float Tva = 0.0f;
    if (tail) {
        int ct_ = (tg + 2 * (cnt - 1)) * 64 + wcol;
        const unsigned short* pT_ = d2b + (size_t)ct_ * CC + lg8;
        Ta0 = *(const short8v*)(pT_);
        Ta1 = *(const short8v*)(pT_ + 32);
        Tva = vism[bNN + ct_];
    }

    CONS2(P, j);
    if (j + 1 < npair) CONS2(Q, j + 1);

    if (tail) {
        int tbT_ = (tg + 2 * (cnt - 1)) * 64;
        f32x4 xT0 = {0,0,0,0}, xT1 = {0,0,0,0};
        xT0 = __builtin_amdgcn_mfma_f32_16x16x32_bf16(afr00, Ta0, xT0, 0,0,0);
        xT0 = __builtin_amdgcn_mfma_f32_16x16x32_bf16(afr01, Ta1, xT0, 0,0,0);
        xT1 = __builtin_amdgcn_mfma_f32_16x16x32_bf16(afr10, Ta0, xT1, 0,0,0);
        xT1 = __builtin_amdgcn_mfma_f32_16x16x32_bf16(afr11, Ta1, xT1, 0,0,0);
        bool slowT_ = (tbT_ + 63 >= lmin) && (tbT_ <= lmax);
        EPI1(xT0, xT1, tbT_, Tva, slowT_);
    }

    // finalize: min over classes, reduce across the 16 l15-lanes sharing each row
    #pragma unroll
    for (int s_ = 0; s_ < 8; s_++) {
        float v0 = sqrtf(fmaxf(2.0f - 2.0f * m0[s_], EPSF));
        float v5 = sqrtf(fmaxf(2.0f - 2.0f * m5[s_], EPSF)) + 5.0f;
        float res = fminf(v0, v5);
        #pragma unroll
        for (int off = 1; off < 16; off <<= 1)
            res = fminf(res, __shfl_xor(res, off));
        if (l15 == 0)
            sres[w * 32 + (s_ >> 2) * 16 + lg * 4 + (s_ & 3)] = res;
    }
    __syncthreads();
    if (tid < 32) {
        float mres = fminf(fminf(sres[tid], sres[32 + tid]),
                           fminf(sres[64 + tid], sres[96 + tid]));
        atomicMin(&negbits[bNN + r0 + tid], __float_as_uint(mres));
    }
}

// ============ final loss (single block) ============
__global__ __launch_bounds__(1024) void k_final(
    const float* __restrict__ posim, const float* __restrict__ matchm,
    const unsigned int* __restrict__ negbits, float* __restrict__ out)
{
    __shared__ float sn[1024], sd[1024];
    int tid = threadIdx.x;
    float num = 0.0f, den = 0.0f;
    for (int i = tid; i < BB * NN; i += 1024) {
        float neg = __uint_as_float(negbits[i]);
        float l = fmaxf(posim[i] - neg + 1.0f, 0.0f);
        float mm = matchm[i];
        num += l * l * mm;
        den += mm;
    }
    sn[tid] = num; sd[tid] = den;
    __syncthreads();
    for (int s = 512; s > 0; s >>= 1) {
        if (tid < s) { sn[tid] += sn[tid + s]; sd[tid] += sd[tid + s]; }
        __syncthreads();
    }
    if (tid == 0) out[0] = sn[0] / sd[0];
}

extern "C" void kernel_launch(void* const* d_in, const int* in_sizes, int n_in,
                              void* d_out, int out_size, void* d_ws, size_t ws_size,
                              hipStream_t stream)
{
    const float* desc1  = (const float*)d_in[2];
    const float* desc2  = (const float*)d_in[3];
    const float* homo12 = (const float*)d_in[4];
    const float* homo21 = (const float*)d_in[5];
    float* out = (float*)d_out;

    float*        vism    = (float*)d_ws;                      // 9600
    float*        posim   = vism + BB * NN;                    // 9600
    float*        matchm  = posim + BB * NN;                   // 9600
    int*          neighpk = (int*)(matchm + BB * NN);          // 9600
    unsigned int* negbits = (unsigned int*)(neighpk + BB * NN);// 9600
    unsigned short* d1bf  = (unsigned short*)(negbits + BB * NN);
    unsigned short* d2bf  = d1bf + (size_t)BB * NN * CC;

    int nb_pre = 2 * BB * NTILES + 2 * BB * NTILES * 4;        // 300 cvt + 2400 percell
    k_pre<<<nb_pre, 256, 0, stream>>>(desc1, desc2, homo12, homo21,
                                      d1bf, d2bf, posim, matchm, vism, neighpk, negbits);
    k_negmin<<<BB * 150 * 2, 256, 0, stream>>>(d1bf, d2bf, vism, neighpk, negbits);
    k_final<<<1, 1024, 0, stream>>>(posim, matchm, negbits, out);
}